// Round 5
// baseline (186.354 us; speedup 1.0000x reference)
//
#include <hip/hip_runtime.h>

typedef unsigned short ushort_t;

#define M_DIM 1024   // 2*512 rows of x
#define N_DIM 4096   // OUT_F
#define K_DIM 4096   // IN_F
#define NFREQ 10000
constexpr float SCALE = 150.0f / 64.0f;   // 150 / sqrt(4096)

typedef __bf16 bf16x8_t  __attribute__((ext_vector_type(8)));
typedef float  f32x16_t  __attribute__((ext_vector_type(16)));

// Native RNE f32->bf16 (R4: measured -2us steady vs bit-twiddle RNE)
__device__ inline ushort_t f2bf(float f) {
  union { __bf16 h; ushort_t u; } v;
  v.h = (__bf16)f;
  return v.u;
}

// ---------------------------------------------------------------------------
// Kernel 1: W' = bf16( weight + s * iwht(scatter(spectrum,idx)) ), plus
// x fp32->bf16 folded in as grid-y slice 0. UNCHANGED from R4 (best known:
// ~50us steady). Ledger: phases1-3 ~5us (R1); ILP prefetch hurts via
// occupancy (R2); 2x slices hurt via redundancy (R3); native cvt -2us (R4).
// ---------------------------------------------------------------------------
__global__ __launch_bounds__(256) void build_w4(
    const float* __restrict__ weight,
    const float* __restrict__ spectrum,
    const int* __restrict__ idx,          // [2][NFREQ]: row 0 = r (out), row 1 = c (in)
    const float* __restrict__ x,
    ushort_t* __restrict__ wb,
    ushort_t* __restrict__ xb) {
  // ---- folded cvt_x slice (dispatched first) ----
  if (blockIdx.y == 0) {
    int flat = blockIdx.x * 256 + threadIdx.x;    // 16384 threads
#pragma unroll 4
    for (int k = 0; k < 64; ++k) {
      int i = flat + k * 16384;                   // M*K/4 = 1048576 float4s
      float4 v = ((const float4*)x)[i];
      ushort4 o;
      o.x = f2bf(v.x); o.y = f2bf(v.y); o.z = f2bf(v.z); o.w = f2bf(v.w);
      ((ushort4*)xb)[i] = o;
    }
    return;
  }

  constexpr int CAP = 1024;
  __shared__ unsigned e_raw[CAP];   // (dc<<26)|(j<<12)|r
  __shared__ float    v_raw[CAP];
  __shared__ uint2    ev_srt[CAP];  // .x = packed meta, .y = float bits
  __shared__ int cnt;
  __shared__ int cstart[65];
  __shared__ int coff[64];
  __shared__ int ccnt[64];
  __shared__ unsigned walsh16[16];  // walsh16[m] bit j = parity(j & m)

  const int tid = threadIdx.x;
  const int ci0 = blockIdx.x * 64;
  const int o0  = (blockIdx.y - 1) * 256;

  if (tid == 0) cnt = 0;
  if (tid < 64) ccnt[tid] = 0;
  if (tid < 16) {
    unsigned m = tid;
    unsigned w = (m & 1 ? 0xAAAAu : 0u) ^ (m & 2 ? 0xCCCCu : 0u)
               ^ (m & 4 ? 0xF0F0u : 0u) ^ (m & 8 ? 0xFF00u : 0u);
    walsh16[m] = w;
  }
  __syncthreads();

  // Phase 1: collect this group's entries
  for (int j = tid; j < NFREQ; j += 256) {
    int c = idx[NFREQ + j];
    if ((c >> 6) == (int)blockIdx.x) {
      int p = atomicAdd(&cnt, 1);
      if (p < CAP) {
        e_raw[p] = ((unsigned)(c & 63) << 26) | ((unsigned)j << 12) | (unsigned)idx[j];
        v_raw[p] = spectrum[j];
        atomicAdd(&ccnt[c & 63], 1);
      }
    }
  }
  __syncthreads();
  const int n = cnt < CAP ? cnt : CAP;

  // Phase 2: prefix sum over 64 column counts (wave 0), then scatter sorted
  if (tid < 64) {
    int v = ccnt[tid];
    int s = v;
    for (int d = 1; d < 64; d <<= 1) {
      int o = __shfl_up(s, d, 64);
      if (tid >= d) s += o;
    }
    cstart[tid + 1] = s;
    if (tid == 0) cstart[0] = 0;
    coff[tid] = s - v;   // exclusive
  }
  __syncthreads();
  for (int e = tid; e < n; e += 256) {
    unsigned w = e_raw[e];
    int dc = w >> 26;
    int p = atomicAdd(&coff[dc], 1);
    ev_srt[p] = make_uint2(w, __float_as_uint(v_raw[e]));
  }
  __syncthreads();

  // Phase 3: last-wins dedup within each column bucket (LDS-local)
  for (int e = tid; e < n; e += 256) {
    uint2 ev = ev_srt[e];
    int dc = ev.x >> 26;
    unsigned r = ev.x & 0xFFFu, j = (ev.x >> 12) & 0x3FFFu;
    int s0 = cstart[dc], e0 = cstart[dc + 1];
    bool dead = false;
    for (int p = s0; p < e0; ++p) {
      unsigned w2 = ev_srt[p].x;
      if ((w2 & 0xFFFu) == r && ((w2 >> 12) & 0x3FFFu) > j) dead = true;
    }
    if (dead) ev_srt[e].y = 0u;   // +0.0f: additive no-op == excluded
  }
  __syncthreads();

  // Phase 4: thread = 4 consecutive cols x 16 CONTIGUOUS rows, entry-outer.
  const int dc0   = (tid & 15) * 4;
  const int rof   = tid >> 4;
  const int obase = o0 + rof * 16;

  float acc[4][16];
#pragma unroll
  for (int c = 0; c < 4; ++c)
#pragma unroll
    for (int j = 0; j < 16; ++j) acc[c][j] = 0.0f;

#pragma unroll
  for (int c = 0; c < 4; ++c) {
    const int s = cstart[dc0 + c], e = cstart[dc0 + c + 1];
    for (int p = s; p < e; ++p) {
      uint2 ev = ev_srt[p];                       // one ds_read_b64 per entry
      unsigned r = ev.x & 0xFFFu;
      unsigned W = walsh16[r & 15u];              // 16-row sign pattern
      unsigned sx = ev.y ^ ((unsigned)(__popc(obase & r) & 1) << 31);  // ±v base sign
#pragma unroll
      for (int j = 0; j < 16; ++j) {
        acc[c][j] += __uint_as_float(sx ^ ((W << (31 - j)) & 0x80000000u));
      }
    }
  }

  // Epilogue: FULL unroll so all acc indices are compile-time (VGPR-resident)
  size_t g = (size_t)obase * K_DIM + ci0 + dc0;
#pragma unroll
  for (int j = 0; j < 16; ++j) {
    float4 w4 = *(const float4*)&weight[g];
    ushort4 ov;
    ov.x = f2bf(w4.x + SCALE * acc[0][j]);
    ov.y = f2bf(w4.y + SCALE * acc[1][j]);
    ov.z = f2bf(w4.z + SCALE * acc[2][j]);
    ov.w = f2bf(w4.w + SCALE * acc[3][j]);
    *(ushort4*)&wb[g] = ov;
    g += K_DIM;
  }
}

// ---------------------------------------------------------------------------
// Kernel 2 (R5 REWRITE): C[M,N] = A[M,K] * B[N,K]^T, deep-pipelined.
// Theory: R1 proved more blocks/CU don't help (zsplit 2->4: 48us flat) ->
// the loss is the per-K-step vmcnt(0)+barrier drain (m97-structure ceiling).
// Cure = T3+T4: counted vmcnt, loads spanning barriers.
//   - 128x256 tile, 512 thr (8 waves as 2M x 4N, wave tile 64x64 unchanged)
//   - 3-deep LDS K-tile buffers (144 KB): during tile t, stage tile t+2 into
//     the buffer holding t-1 (fully consumed at the t-1 -> t barrier) ->
//     race-free by construction, 2-tile (~2x compute-phase) latency lead.
//   - ONE barrier per K-tile; end-of-tile s_waitcnt vmcnt(6) (= 6 loads of
//     tile t+2 may stay in flight; tile t+1's 6 are the oldest and retire).
//     vmcnt(0) only at the final drain. sched_barrier(0) fences prevent the
//     compiler hoisting/sinking staging loads across the counted wait.
//   - setprio(1) around the MFMA cluster (T5).
// Grid 16x8x2 = 256 blocks = exactly 1/CU (LDS 144KB forces 1/CU; by-design).
// MFMA floor 13.7us, LDS pipe ~= MFMA pipe 1:1; target ~32us from 48.
// ---------------------------------------------------------------------------
__global__ __launch_bounds__(512) void gemm_pipe(
    const ushort_t* __restrict__ A,   // xb [M,K]
    const ushort_t* __restrict__ B,   // wb [N,K]
    float* __restrict__ C0,
    float* __restrict__ C1,
    int klen) {
  constexpr int BM = 128, BN = 256, BK = 64;
  constexpr int A_US = BM * BK;          // 8192 ushorts per buffer (16 KB)
  constexpr int B_US = BN * BK;          // 16384 ushorts per buffer (32 KB)
  __shared__ __align__(16) ushort_t lds[3 * (A_US + B_US)];   // 144 KB

  const int tid  = threadIdx.x;
  const int wave = tid >> 6, lane = tid & 63;
  const int wrow = wave >> 2;          // 0..1  (M)
  const int wcol = wave & 3;           // 0..3  (N)
  const int l32  = lane & 31, half = lane >> 5;

  // XCD-aware swizzle, bijective on the 16x8 xy-grid: xcd c gets a 4x4 chunk
  const int fid = blockIdx.y * 16 + blockIdx.x;    // 0..127 within z-slice
  const int xcd = fid & 7, w16 = fid >> 3;         // 0..7, 0..15
  const int bn = ((xcd & 3) * 4 + (w16 & 3)) * BN;         // 16 n-blocks
  const int bm = ((xcd >> 2) * 4 + (w16 >> 2)) * BM;       // 8 m-blocks

  const int kbeg = blockIdx.z * klen;
  const int nt   = klen / BK;
  float* __restrict__ dst = blockIdx.z == 0
      ? C0 : C1 + (size_t)(blockIdx.z - 1) * M_DIM * N_DIM;

  // stage tile tt into buffer p: 48 KB = 512 thr x 6 x 16B global_load_lds.
  // LDS dest is linear (wave-uniform base + lane*16, m104); the XOR swizzle
  // is applied on the per-lane GLOBAL source quad (m173 pattern).
  auto stage = [&](int tt, int p) {
    const int kt = kbeg + tt * BK;
    ushort_t* abase = lds + p * A_US;
    ushort_t* bbase = lds + 3 * A_US + p * B_US;
#pragma unroll
    for (int l = 0; l < 6; ++l) {
      int s  = tid + l * 512;                  // per-lane slot
      int sb = (tid & ~63) + l * 512;          // wave-uniform slot base
      if (l < 2) {                             // A: slots 0..1023
        int gr = s >> 3, qg = (s & 7) ^ (gr & 7);
        const ushort_t* ga = A + (size_t)(bm + gr) * K_DIM + kt + qg * 8;
        __builtin_amdgcn_global_load_lds(
            (const __attribute__((address_space(1))) void*)ga,
            (__attribute__((address_space(3))) void*)(abase + sb * 8), 16, 0, 0);
      } else {                                 // B: slots 1024..3071
        int s2 = s - 1024;
        int gr = s2 >> 3, qg = (s2 & 7) ^ (gr & 7);
        const ushort_t* gb = B + (size_t)(bn + gr) * K_DIM + kt + qg * 8;
        __builtin_amdgcn_global_load_lds(
            (const __attribute__((address_space(1))) void*)gb,
            (__attribute__((address_space(3))) void*)(bbase + (sb - 1024) * 8), 16, 0, 0);
      }
    }
  };

  f32x16_t acc[2][2] = {};

  // ---- prologue: stage tiles 0 and 1, wait for tile 0 (own-wave) + barrier
  stage(0, 0);
  if (nt > 1) {
    stage(1, 1);
    __builtin_amdgcn_sched_barrier(0);
    asm volatile("s_waitcnt vmcnt(6)" ::: "memory");   // tile0's 6 are oldest
  } else {
    __builtin_amdgcn_sched_barrier(0);
    asm volatile("s_waitcnt vmcnt(0)" ::: "memory");
  }
  __builtin_amdgcn_sched_barrier(0);
  __builtin_amdgcn_s_barrier();
  __builtin_amdgcn_sched_barrier(0);

  for (int t = 0; t < nt; ++t) {
    const int cb = t % 3;
    const ushort_t* as_ = lds + cb * A_US;
    const ushort_t* bs_ = lds + 3 * A_US + cb * B_US;

    // issue next-next tile's loads first (into the buffer tile t-1 vacated)
    if (t + 2 < nt) stage(t + 2, (t + 2) % 3);

    // fragment loads from buf[t%3] (resident since the last barrier)
    bf16x8_t af[2][4], bfr[2][4];
#pragma unroll
    for (int mi = 0; mi < 2; ++mi) {
      int ar = wrow * 64 + mi * 32 + l32;
#pragma unroll
      for (int h = 0; h < 4; ++h) {
        int q = h * 2 + half;
        af[mi][h] = *(const bf16x8_t*)&as_[ar * BK + ((q ^ (ar & 7)) * 8)];
      }
    }
#pragma unroll
    for (int nj = 0; nj < 2; ++nj) {
      int br = wcol * 64 + nj * 32 + l32;
#pragma unroll
      for (int h = 0; h < 4; ++h) {
        int q = h * 2 + half;
        bfr[nj][h] = *(const bf16x8_t*)&bs_[br * BK + ((q ^ (br & 7)) * 8)];
      }
    }

    __builtin_amdgcn_s_setprio(1);
#pragma unroll
    for (int h = 0; h < 4; ++h)
#pragma unroll
      for (int mi = 0; mi < 2; ++mi)
#pragma unroll
        for (int nj = 0; nj < 2; ++nj)
          acc[mi][nj] = __builtin_amdgcn_mfma_f32_32x32x16_bf16(
              af[mi][h], bfr[nj][h], acc[mi][nj], 0, 0, 0);
    __builtin_amdgcn_s_setprio(0);

    // end-of-tile: counted wait (never 0 mid-loop) + single barrier
    if (t + 2 < nt) {
      __builtin_amdgcn_sched_barrier(0);
      asm volatile("s_waitcnt vmcnt(6)" ::: "memory");  // t+1's 6 retire
      __builtin_amdgcn_sched_barrier(0);
      __builtin_amdgcn_s_barrier();
      __builtin_amdgcn_sched_barrier(0);
    } else if (t + 1 < nt) {
      __builtin_amdgcn_sched_barrier(0);
      asm volatile("s_waitcnt vmcnt(0)" ::: "memory");  // final drain
      __builtin_amdgcn_sched_barrier(0);
      __builtin_amdgcn_s_barrier();
      __builtin_amdgcn_sched_barrier(0);
    }
  }

  // epilogue: col = lane&31, row = (reg&3) + 8*(reg>>2) + 4*half (verified)
#pragma unroll
  for (int mi = 0; mi < 2; ++mi) {
#pragma unroll
    for (int nj = 0; nj < 2; ++nj) {
      int col  = bn + wcol * 64 + nj * 32 + l32;
      int rwb  = bm + wrow * 64 + mi * 32 + 4 * half;
#pragma unroll
      for (int reg = 0; reg < 16; ++reg) {
        int row = rwb + (reg & 3) + 8 * (reg >> 2);
        dst[(size_t)row * N_DIM + col] = acc[mi][nj][reg];
      }
    }
  }
}

// ---------------------------------------------------------------------------
// Kernel 3: out += sum of npart partial arrays (float4)
// ---------------------------------------------------------------------------
__global__ __launch_bounds__(256) void reduce_n(float* __restrict__ out,
                                                const float* __restrict__ part,
                                                int npart) {
  int i = blockIdx.x * 256 + threadIdx.x;
  float4 a = ((const float4*)out)[i];
  for (int t = 0; t < npart; ++t) {
    float4 b = ((const float4*)(part + (size_t)t * M_DIM * N_DIM))[i];
    a.x += b.x; a.y += b.y; a.z += b.z; a.w += b.w;
  }
  ((float4*)out)[i] = a;
}

extern "C" void kernel_launch(void* const* d_in, const int* in_sizes, int n_in,
                              void* d_out, int out_size, void* d_ws, size_t ws_size,
                              hipStream_t stream) {
  const float* x        = (const float*)d_in[0];   // [2,512,4096]
  const float* weight   = (const float*)d_in[1];   // [4096,4096]
  const float* spectrum = (const float*)d_in[2];   // [10000]
  const int*   indices  = (const int*)d_in[3];     // [2,10000]
  float* out = (float*)d_out;                      // [2,512,4096]

  char* ws = (char*)d_ws;
  const size_t WB_BYTES = (size_t)N_DIM * K_DIM * 2;   // 32 MB
  const size_t XB_BYTES = (size_t)M_DIM * K_DIM * 2;   //  8 MB
  const size_t P1_BYTES = (size_t)M_DIM * N_DIM * 4;   // 16 MB per partial

  ushort_t* wb = (ushort_t*)ws;
  ushort_t* xb = (ushort_t*)(ws + WB_BYTES);
  float* part = (float*)(ws + WB_BYTES + XB_BYTES);

  int zsplit = (ws_size >= WB_BYTES + XB_BYTES + P1_BYTES) ? 2 : 1;

  // convert x (y=0, dispatched first) + build W' (y=1..16) in one dispatch
  build_w4<<<dim3(64, 17), 256, 0, stream>>>(weight, spectrum, indices, x, wb, xb);

  // 16 x 8 x zsplit = 256 blocks at zsplit=2: exactly one per CU, no tail
  gemm_pipe<<<dim3(N_DIM / 256, M_DIM / 128, zsplit), 512, 0, stream>>>(
      xb, wb, out, part, K_DIM / zsplit);
  if (zsplit > 1)
    reduce_n<<<(M_DIM * N_DIM / 4) / 256, 256, 0, stream>>>(out, part, zsplit - 1);
}